// Round 2
// baseline (86.530 us; speedup 1.0000x reference)
//
#include <hip/hip_runtime.h>
#include <stdint.h>

#define NTIPS 128
#define NSITES 1024
#define BS 32
#define STEPS 127   // ntips-1 postorder merge steps
#define SB 64       // sites per block (one wave, one site per lane)

// Pack one-hot int32 L[tip][5][site] -> 5-bit mask byte packed[tip][site].
__global__ __launch_bounds__(256) void pack_leaves(const int* __restrict__ L,
                                                   uint8_t* __restrict__ packed) {
    int i = blockIdx.x * 256 + threadIdx.x;       // 0 .. 128*1024-1
    int tip = i >> 10, site = i & 1023;
    const int* b = L + tip * 5 * NSITES + site;
    int m = b[0] | (b[NSITES] << 1) | (b[2 * NSITES] << 2) |
            (b[3 * NSITES] << 3) | (b[4 * NSITES] << 4);
    packed[i] = (uint8_t)m;
}

__global__ __launch_bounds__(64) void fitch_kernel(const int* __restrict__ L,
                                                   const int* __restrict__ site_counts,
                                                   const int* __restrict__ pairs,
                                                   const uint8_t* __restrict__ packed,
                                                   int use_packed,
                                                   int* __restrict__ out) {
    __shared__ int     leafm[NTIPS][SB];      // 32 KiB, [tip][lane] -> conflict-free
    __shared__ uint8_t internal[STEPS][SB];   // ~8 KiB, per-lane private columns
    __shared__ int     spairs[STEPS * 3];     // this batch's (c0,c1,p) triples

    const int tid      = threadIdx.x;
    const int batch    = blockIdx.x >> 4;       // 32 batches
    const int siteBase = (blockIdx.x & 15) * SB;
    const int site     = siteBase + tid;

    // Stage this batch's pairs: pairs[step][batch][j], flat = step*96 + batch*3 + j
    for (int i = tid; i < STEPS * 3; i += 64) {
        int s = i / 3, j = i - s * 3;
        spairs[i] = pairs[s * (BS * 3) + batch * 3 + j];
    }

    // Stage leaf masks for this block's 64 sites.
    if (use_packed) {
        // 8 KB of packed bytes -> unpack to int lanes. 2048 dwords / 64 lanes.
        for (int i = tid; i < NTIPS * (SB / 4); i += 64) {
            int tip = i >> 4, j = i & 15;
            unsigned d = ((const unsigned*)(packed + (tip << 10) + siteBase))[j];
            int4 v = make_int4(d & 255, (d >> 8) & 255, (d >> 16) & 255, (d >> 24) & 255);
            *(int4*)&leafm[tip][j * 4] = v;
        }
    } else {
        // Fallback: build masks straight from one-hot L (coalesced dword loads).
        for (int tip = 0; tip < NTIPS; ++tip) {
            const int* b = L + tip * 5 * NSITES + site;
            leafm[tip][tid] = b[0] | (b[NSITES] << 1) | (b[2 * NSITES] << 2) |
                              (b[3 * NSITES] << 3) | (b[4 * NSITES] << 4);
        }
    }
    __syncthreads();

    // 127 sequential Fitch merges. Pair data is wave-uniform -> force SGPR so
    // the child-source selection becomes scalar branches (loads skipped, not
    // predicated). lastP/lastV register-forwards the caterpillar chain so the
    // loop-carried dependence never round-trips through LDS.
    int lastP = -1;
    int lastV = 0;
    int score = 0;
    for (int s = 0; s < STEPS; ++s) {
        int c0 = __builtin_amdgcn_readfirstlane(spairs[3 * s]);
        int c1 = __builtin_amdgcn_readfirstlane(spairs[3 * s + 1]);
        int p  = __builtin_amdgcn_readfirstlane(spairs[3 * s + 2]);
        int m0, m1;
        if (c0 == lastP)     m0 = lastV;
        else if (c0 < NTIPS) m0 = leafm[c0][tid];
        else                 m0 = (int)internal[c0 - NTIPS][tid];
        if (c1 == lastP)     m1 = lastV;
        else if (c1 < NTIPS) m1 = leafm[c1][tid];
        else                 m1 = (int)internal[c1 - NTIPS][tid];
        int inter = m0 & m1;
        int nxt   = inter ? inter : (m0 | m1);   // empty -> union, else intersection
        score    += (inter == 0);
        internal[p - NTIPS][tid] = (uint8_t)nxt; // fire-and-forget store (generality)
        lastP = p;
        lastV = nxt;
    }

    // Weighted per-site score -> per-batch sum. int32-exact (max < 2^24).
    int val = score * site_counts[site];
    #pragma unroll
    for (int off = 32; off; off >>= 1) val += __shfl_down(val, off);
    if (tid == 0) atomicAdd(&out[batch], val);
}

extern "C" void kernel_launch(void* const* d_in, const int* in_sizes, int n_in,
                              void* d_out, int out_size, void* d_ws, size_t ws_size,
                              hipStream_t stream) {
    const int* L           = (const int*)d_in[0];
    const int* site_counts = (const int*)d_in[1];
    const int* pairs       = (const int*)d_in[2];
    int* out               = (int*)d_out;

    // Harness poisons d_out with 0xAA before every launch -> zero it (capture-safe).
    hipMemsetAsync(out, 0, BS * sizeof(int), stream);

    const size_t packed_bytes = (size_t)NTIPS * NSITES;  // 128 KiB
    int use_packed = (ws_size >= packed_bytes) ? 1 : 0;
    uint8_t* packed = (uint8_t*)d_ws;

    if (use_packed) {
        pack_leaves<<<dim3((NTIPS * NSITES) / 256), dim3(256), 0, stream>>>(L, packed);
    }
    fitch_kernel<<<dim3(BS * (NSITES / SB)), dim3(64), 0, stream>>>(
        L, site_counts, pairs, packed, use_packed, out);
}